// Round 6
// baseline (471.281 us; speedup 1.0000x reference)
//
#include <hip/hip_runtime.h>
#include <cstdint>

// TTLinear: y = x @ W^T + bias, W (4096x4096) reconstructed from TT cores,
// then a bf16 MFMA GEMM.
//
// R9 = R8 resubmitted verbatim (R8's bench was an infra failure: "container
// failed twice", no compile/test/profile output). Sync audit re-done: barrier
// counts uniform (PRE compile-time), every old-buffer ds_read drains at an
// LGKM0 preceding the barrier gating its overwrite, every staged half is
// VMW(4)+BAR-covered before any wave reads it. Design rationale below.
//
// R8: software-pipelined fragment reads. R7's {read -> bar -> lgkm0 -> MFMA}
// phases serialized the LDS port against the matrix pipe (measured tile time
// ~= port cycles + MFMA cycles = sum, MfmaUtil 50%). R8 keeps the 2-buffer /
// BK=64 / 4-quadrant structure but issues each ds_read batch one phase ahead,
// right after the MFMA cluster that last reads its destination regs
// (quadrant order Q1=(M0N0),Q2=(M0N1),Q3=(M1N0),Q4=(M1N1) nests lifetimes:
// A0 dies after Q2 -> A1 reuses the same 8-frag set; b0 dies after Q3).
// Read issue: B1@P1-end, A1@P2-end, B0'@P3-end, A0'@P4-end (4/8/4/8 per
// phase, balanced). Each batch flows through the LDS port while the matrix
// pipe drains the previous quadrant; every lgkm(0) then returns ~immediately.
// Staging: 4 gloads @P1 (A0',B0'), 4 @P2 (B1',A1'); vmcnt(4) at P1-mid
// (retires B1',A1', 3-phase budget) and P3-top (retires A0',B0', 2-phase
// budget). 2 barriers/tile. sched_barrier(0) after each lgkm0 (rule-18
// MFMA-hoist guard). Same reads/MFMAs/acc order as R7 -> bit-identical.
//
// ws layout: [0,64MiB) xb bf16, [64MiB,96MiB) Wbt bf16 (N x K), then C01 fp32.

typedef __bf16 bf16x8 __attribute__((ext_vector_type(8)));
typedef float f32x4 __attribute__((ext_vector_type(4)));
typedef unsigned short u16;
typedef u16 u16x8 __attribute__((ext_vector_type(8)));

__device__ __forceinline__ u16 f2bf(float f) {
    unsigned u = __builtin_bit_cast(unsigned, f);
    u += 0x7fffu + ((u >> 16) & 1u);   // round-to-nearest-even
    return (u16)(u >> 16);
}

// ---- kernel 1: x fp32 -> bf16 (8 elems/thread, 16B stores) ----
__global__ void k_cvt(const float* __restrict__ x, u16* __restrict__ xb) {
    long i = (long)blockIdx.x * blockDim.x + threadIdx.x;   // one per 8 floats
    const float4* p = (const float4*)x;
    float4 a = p[2 * i], b = p[2 * i + 1];
    u16x8 o;
    o[0] = f2bf(a.x); o[1] = f2bf(a.y); o[2] = f2bf(a.z); o[3] = f2bf(a.w);
    o[4] = f2bf(b.x); o[5] = f2bf(b.y); o[6] = f2bf(b.z); o[7] = f2bf(b.w);
    ((u16x8*)xb)[i] = o;
}

// ---- kernel 2: C01[o0][o1][i0][i1][b2] = sum_b1 core0[0,o0,i0,b1]*core1[b1,o1,i1,b2]
__global__ void k_c01(const float* __restrict__ c0, const float* __restrict__ c1,
                      float* __restrict__ c01) {
    int idx = blockIdx.x * 256 + threadIdx.x;   // 524288 total
    int b2 = idx & 7, i1 = (idx >> 3) & 15, i0 = (idx >> 7) & 15;
    int o1 = (idx >> 11) & 15, o0 = idx >> 15;
    float s = 0.f;
#pragma unroll
    for (int b1 = 0; b1 < 8; ++b1)
        s += c0[(o0 * 16 + i0) * 8 + b1] * c1[((b1 * 16 + o1) * 16 + i1) * 8 + b2];
    c01[idx] = s;
}

// ---- kernel 3: Wbt[o][i] bf16 (B^T layout, N x K); thread computes 8 consecutive i
__global__ void k_w(const float* __restrict__ c01, const float* __restrict__ c2,
                    u16* __restrict__ wbt) {
    int idx = blockIdx.x * 256 + threadIdx.x;   // 2,097,152 total
    int i2h = idx & 1;
    int i1 = (idx >> 1) & 15;
    int i0 = (idx >> 5) & 15;
    int o = idx >> 9;                            // 0..4095
    int o2 = o & 15, o1 = (o >> 4) & 15, o0 = o >> 8;
    const float* c = &c01[(((o0 * 16 + o1) * 16 + i0) * 16 + i1) * 8];
    float acc[8] = {0, 0, 0, 0, 0, 0, 0, 0};
#pragma unroll
    for (int b2 = 0; b2 < 8; ++b2) {
        float cv = c[b2];
        const float* cc = &c2[(b2 * 16 + o2) * 16 + i2h * 8];
#pragma unroll
        for (int j = 0; j < 8; ++j) acc[j] += cv * cc[j];
    }
    u16x8 ov;
#pragma unroll
    for (int j = 0; j < 8; ++j) ov[j] = f2bf(acc[j]);
    ((u16x8*)wbt)[(long)o * 512 + (i0 * 32 + i1 * 2 + i2h)] = ov;
}

// ---- kernel 4: GEMM. C[m][n] = sum_k A[m,k]*B[n,k] + bias[n] ----
#define BM 256
#define BN 256
#define BK 64
#define TILEU (BM * BK)                 // 16384 u16 = 32 KiB per operand buf
#define LDS_BYTES (4 * TILEU * 2)       // 2 bufs x (A+B) x 2B = 131072

static_assert(LDS_BYTES == 131072, "lds size");

__device__ __forceinline__ void gload_lds16(const void* g, void* l) {
    __builtin_amdgcn_global_load_lds(
        (const __attribute__((address_space(1))) unsigned*)g,
        (__attribute__((address_space(3))) unsigned*)l, 16, 0, 0);
}

#define VMW(N) asm volatile("s_waitcnt vmcnt(" #N ")" ::: "memory")
#define LGKM0  asm volatile("s_waitcnt lgkmcnt(0)" ::: "memory")
#define BAR()  __builtin_amdgcn_s_barrier()
#define SCHED0 __builtin_amdgcn_sched_barrier(0)

// read A phase-half H (8 x ds_read_b128) from BASE into DST[8]
#define READ_A(H, DST, BASE) do { \
    _Pragma("unroll") for (int mi_ = 0; mi_ < 4; ++mi_) { \
        DST[mi_ * 2 + 0] = *(const bf16x8*)&(BASE)[arow + ((H) * 128 + mi_ * 16) * 64 + swz0]; \
        DST[mi_ * 2 + 1] = *(const bf16x8*)&(BASE)[arow + ((H) * 128 + mi_ * 16) * 64 + swz1]; \
    } } while (0)

// read B phase-half G (4 x ds_read_b128) from BASE into DST[4]
#define READ_B(G, DST, BASE) do { \
    _Pragma("unroll") for (int ni_ = 0; ni_ < 2; ++ni_) { \
        DST[ni_ * 2 + 0] = *(const bf16x8*)&(BASE)[brow + ((G) * 128 + ni_ * 16) * 64 + swz0]; \
        DST[ni_ * 2 + 1] = *(const bf16x8*)&(BASE)[brow + ((G) * 128 + ni_ * 16) * 64 + swz1]; \
    } } while (0)

// one C-quadrant: 16 MFMA (4 Mfrag x 2 Nfrag x 2 kk), kk ascending = K order
#define MFMA16(ASET, BF, H, G) do { \
    __builtin_amdgcn_s_setprio(1); \
    _Pragma("unroll") for (int mi_ = 0; mi_ < 4; ++mi_) \
    _Pragma("unroll") for (int ni_ = 0; ni_ < 2; ++ni_) \
    _Pragma("unroll") for (int kk_ = 0; kk_ < 2; ++kk_) \
        acc[(H) * 4 + mi_][(G) * 2 + ni_] = __builtin_amdgcn_mfma_f32_16x16x32_bf16( \
            ASET[mi_ * 2 + kk_], BF[ni_ * 2 + kk_], acc[(H) * 4 + mi_][(G) * 2 + ni_], 0, 0, 0); \
    __builtin_amdgcn_s_setprio(0); \
} while (0)

// One K-tile. Reads buf BUF; stages tile TT+1 into buf 1-BUF (when PRE).
// Quadrants Q1..Q4 = (M0N0),(M0N1),(M1N0),(M1N1). Operand lifetimes nest:
// A0 in aA dies after Q2 -> A1 reuses aA; b0 dies after Q3; b1 lives to Q4.
// Each ds_read batch issues right after the MFMA cluster that last reads its
// dest regs (WAR-enforced) and one phase before its lgkm0 -> port overlaps
// matrix drain. VM invariant (steady): entering P1 outstanding = {B1',A1'}=4;
// P1 stages A0',B0' (->8), VMW(4) retires B1',A1'; P2 stages B1',A1' (->8);
// P3-top VMW(4) retires A0',B0' (read by B0P/A0P prefetch after BAR#2).
#define TILE(BUF, TT, PRE) do { \
    const u16* aT = lds + (BUF) * TILEU; \
    const u16* bT = lds + 2 * TILEU + (BUF) * TILEU; \
    u16* sA = lds + (1 - (BUF)) * TILEU; \
    u16* sB = lds + 2 * TILEU + (1 - (BUF)) * TILEU; \
    const long ko = (long)((TT) + 1) * BK; \
    /* P1: stage A0',B0' | Q1 = A0 x B0 | retire B1',A1' | issue B1 reads */ \
    if (PRE) { gload_lds16(pa[0] + ko, sA + t * 8); \
               gload_lds16(pa[1] + ko, sA + 4096 + t * 8); \
               gload_lds16(pb[0] + ko, sB + t * 8); \
               gload_lds16(pb[1] + ko, sB + 4096 + t * 8); } \
    LGKM0; SCHED0; \
    MFMA16(aA, b0, 0, 0); \
    if (PRE) { VMW(4); } else { VMW(0); } \
    BAR(); \
    READ_B(1, b1, bT); \
    /* P2: stage B1',A1' | Q2 = A0 x B1 | issue A1 reads (aA WAR after Q2) */ \
    if (PRE) { gload_lds16(pb[2] + ko, sB + 8192 + t * 8); \
               gload_lds16(pb[3] + ko, sB + 12288 + t * 8); \
               gload_lds16(pa[2] + ko, sA + 8192 + t * 8); \
               gload_lds16(pa[3] + ko, sA + 12288 + t * 8); } \
    LGKM0; SCHED0; \
    MFMA16(aA, b1, 0, 1); \
    READ_A(1, aA, aT); \
    /* P3: retire A0',B0'; BAR#2 | Q3 = A1 x B0 | issue B0' prefetch reads */ \
    if (PRE) { VMW(4); BAR(); } \
    LGKM0; SCHED0; \
    MFMA16(aA, b0, 1, 0); \
    if (PRE) { READ_B(0, b0, sB); } \
    /* P4: Q4 = A1 x B1 | issue A0' prefetch reads (next tile's A0) */ \
    MFMA16(aA, b1, 1, 1); \
    if (PRE) { READ_A(0, aA, sA); } \
} while (0)

__launch_bounds__(512, 2)
__global__ void k_gemm(const u16* __restrict__ A, const u16* __restrict__ B,
                       const float* __restrict__ bias, float* __restrict__ C,
                       int M, int N, int K) {
    extern __shared__ __align__(16) u16 lds[];

    // XCD-aware swizzle: 512 blocks, 8 XCDs, 64 blocks/chunk (bijective).
    const int wg = blockIdx.x;
    const int swzb = (wg & 7) * 64 + (wg >> 3);
    const int bn = swzb & 15, bm = swzb >> 4;     // 16 N-blocks x 32 M-blocks
    const int m0 = bm * BM, n0 = bn * BN;

    const int t = threadIdx.x;
    const int wave = t >> 6, lane = t & 63;
    const int wm = wave >> 2, wn = wave & 3;      // 2 (M) x 4 (N) waves
    const int lr = lane & 15, quad = lane >> 4;

    // Staging with phase-permuted row layout (verified R7). Thread loads
    // chunks ci = j*512+t (j=0..3); LDS linear in ci. LDS row lrow = ci>>3:
    //   A: rA = ((lrow>>6)&1)*128 + (lrow>>7)*64 + (lrow&63)
    //   B: rB = ((lrow>>5)&3)*64 + (lrow>>7)*32 + (lrow&31)
    // Chunk swizzle: lds slot (ci&7) holds global chunk (ci&7)^(lrow&7).
    const u16 *pa[4], *pb[4];
#pragma unroll
    for (int j = 0; j < 4; ++j) {
        int ci = j * 512 + t;
        int lrow = ci >> 3;
        int c = (ci & 7) ^ (lrow & 7);
        int rA = ((lrow >> 6) & 1) * 128 + (lrow >> 7) * 64 + (lrow & 63);
        int rB = ((lrow >> 5) & 3) * 64 + (lrow >> 7) * 32 + (lrow & 31);
        pa[j] = &A[(long)(m0 + rA) * K + c * 8];
        pb[j] = &B[(long)(n0 + rB) * K + c * 8];
    }

    // Fragment-read constants (verified R7: 0 bank conflicts).
    const int swz0 = ((quad    ) ^ (lr & 7)) * 8;
    const int swz1 = ((quad + 4) ^ (lr & 7)) * 8;
    const int arow = (wm * 64 + lr) * 64;         // + H*128*64 in READ_A
    const int brow = (wn * 32 + lr) * 64;         // + G*128*64 in READ_B

    f32x4 acc[8][4];
#pragma unroll
    for (int mi = 0; mi < 8; ++mi)
#pragma unroll
        for (int ni = 0; ni < 4; ++ni) acc[mi][ni] = 0.f;

    bf16x8 aA[8], b0[4], b1[4];

    // Prologue: stage tile 0 -> buf0 (order A0,B0,B1,A1), drain once,
    // then issue tile-0 A0/B0 fragment reads (waited by t0-P1's lgkm0).
    gload_lds16(pa[0], lds + t * 8);
    gload_lds16(pa[1], lds + 4096 + t * 8);
    gload_lds16(pb[0], lds + 2 * TILEU + t * 8);
    gload_lds16(pb[1], lds + 2 * TILEU + 4096 + t * 8);
    gload_lds16(pb[2], lds + 2 * TILEU + 8192 + t * 8);
    gload_lds16(pb[3], lds + 2 * TILEU + 12288 + t * 8);
    gload_lds16(pa[2], lds + 8192 + t * 8);
    gload_lds16(pa[3], lds + 12288 + t * 8);
    VMW(0); BAR();
    READ_A(0, aA, lds);
    READ_B(0, b0, (lds + 2 * TILEU));

    // K = 4096 -> 64 tiles: 31 unrolled pairs + tiles 62 (PRE) and 63 (tail).
#pragma unroll 1
    for (int tt = 0; tt < 62; tt += 2) {
        TILE(0, tt,     1);
        TILE(1, tt + 1, 1);
    }
    TILE(0, 62, 1);
    TILE(1, 63, 0);

    // Epilogue: D row = quad*4 + r (m), col = lr (n); add bias, store fp32.
#pragma unroll
    for (int ni = 0; ni < 4; ++ni) {
        int gn = n0 + wn * 64 + ni * 16 + lr;
        float bv = bias[gn];
#pragma unroll
        for (int mi = 0; mi < 8; ++mi) {
            int gm = m0 + wm * 128 + mi * 16 + quad * 4;
#pragma unroll
            for (int r = 0; r < 4; ++r)
                C[(long)(gm + r) * N + gn] = acc[mi][ni][r] + bv;
        }
    }
}

extern "C" void kernel_launch(void* const* d_in, const int* in_sizes, int n_in,
                              void* d_out, int out_size, void* d_ws, size_t ws_size,
                              hipStream_t stream) {
    const float* x = (const float*)d_in[0];
    const float* c0 = (const float*)d_in[1];
    const float* c1 = (const float*)d_in[2];
    const float* c2 = (const float*)d_in[3];
    const float* bias = (const float*)d_in[4];
    float* out = (float*)d_out;

    const int Mb = 8192, Nf = 4096, Kf = 4096;
    char* ws = (char*)d_ws;
    u16* xb = (u16*)ws;                                       // 67,108,864 B
    u16* wbt = (u16*)(ws + 67108864);                         // 33,554,432 B
    float* c01 = (float*)(ws + 67108864 + 33554432);          //  2,097,152 B

    // 128 KiB dynamic LDS (> 64 KiB static limit). Idempotent, capture-safe.
    hipFuncSetAttribute(reinterpret_cast<const void*>(k_gemm),
                        hipFuncAttributeMaxDynamicSharedMemorySize, LDS_BYTES);

    k_cvt<<<dim3((Mb * Kf / 8) / 256), 256, 0, stream>>>(x, xb);
    k_c01<<<dim3(2048), 256, 0, stream>>>(c0, c1, c01);
    k_w<<<dim3(8192), 256, 0, stream>>>(c01, c2, wbt);
    k_gemm<<<dim3((Mb / BM) * (Nf / BN)), dim3(512), LDS_BYTES, stream>>>(
        xb, wbt, bias, out, Mb, Nf, Kf);
}